// Round 3
// baseline (696.142 us; speedup 1.0000x reference)
//
#include <hip/hip_runtime.h>
#include <hip/hip_bf16.h>
#include <hip/hip_cooperative_groups.h>

namespace cg = cooperative_groups;

// COO SpMM: out[row[e], :] += ev[e] * x[col[e], :]
// N=100000, E=1600000, D=128 fp32.
//
// Round 3: all CSR preprocessing in ONE cooperative kernel (grid.sync between
// phases); rank captured from the histogram atomicAdd return value so the
// scatter phase needs no atomics. Gather kernel: NT loads on packed stream,
// NT stores on out, unroll x4.

#define D_FEAT 128
#define COOP_BLOCKS 1024
#define COOP_THREADS 256

typedef float f32x2 __attribute__((ext_vector_type(2)));

// ---------------- cooperative CSR build ----------------

__global__ __launch_bounds__(COOP_THREADS) void build_csr_coop(
    const int* __restrict__ rows, const int* __restrict__ cols,
    const float* __restrict__ w,
    int* __restrict__ start,     // N+1
    int* __restrict__ bsums,     // 512
    int* __restrict__ rank,      // E
    int2* __restrict__ packed,   // E
    int N, int E, int ntiles) {
    cg::grid_group grid = cg::this_grid();
    int tid = threadIdx.x;
    int gid = blockIdx.x * COOP_THREADS + tid;
    int gsz = gridDim.x * COOP_THREADS;
    __shared__ int tmp[512];

    // A: zero counts
    for (int i = gid; i < N + 1; i += gsz) start[i] = 0;
    grid.sync();

    // B: histogram; atomicAdd's return value IS this edge's rank within its row
    for (int e = gid; e < E; e += gsz)
        rank[e] = atomicAdd(&start[rows[e]], 1);
    grid.sync();

    // C1: per-tile (256 counts) exclusive scan in place; tile totals -> bsums
    for (int tile = blockIdx.x; tile < ntiles; tile += gridDim.x) {
        int i = tile * 256 + tid;
        int v = (i < N) ? start[i] : 0;
        tmp[tid] = v;
        __syncthreads();
        for (int off = 1; off < 256; off <<= 1) {
            int t = (tid >= off) ? tmp[tid - off] : 0;
            __syncthreads();
            tmp[tid] += t;
            __syncthreads();
        }
        if (i < N) start[i] = tmp[tid] - v;   // exclusive within tile
        if (tid == 255) bsums[tile] = tmp[255];
        __syncthreads();
    }
    grid.sync();

    // C2: block 0 exclusive-scans bsums (ntiles <= 512), Blelloch over 512
    if (blockIdx.x == 0) {
        tmp[tid]       = (tid < ntiles)       ? bsums[tid]       : 0;
        tmp[tid + 256] = (tid + 256 < ntiles) ? bsums[tid + 256] : 0;
        int offset = 1;
        for (int d = 256; d > 0; d >>= 1) {
            __syncthreads();
            if (tid < d) {
                int ai = offset * (2 * tid + 1) - 1;
                int bi = offset * (2 * tid + 2) - 1;
                tmp[bi] += tmp[ai];
            }
            offset <<= 1;
        }
        __syncthreads();
        if (tid == 0) tmp[511] = 0;
        for (int d = 1; d < 512; d <<= 1) {
            offset >>= 1;
            __syncthreads();
            if (tid < d) {
                int ai = offset * (2 * tid + 1) - 1;
                int bi = offset * (2 * tid + 2) - 1;
                int t = tmp[ai]; tmp[ai] = tmp[bi]; tmp[bi] += t;
            }
        }
        __syncthreads();
        if (tid < ntiles)       bsums[tid]       = tmp[tid];
        if (tid + 256 < ntiles) bsums[tid + 256] = tmp[tid + 256];
    }
    grid.sync();

    // C3: add scanned tile offsets; set start[N] = E
    for (int i = gid; i < N; i += gsz)
        start[i] += bsums[i >> 8];
    if (gid == 0) start[N] = E;
    grid.sync();

    // D: scatter edges to sorted slots (no atomics: slot = start + rank)
    for (int e = gid; e < E; e += gsz) {
        int slot = start[rows[e]] + rank[e];
        int2 cw;
        cw.x = cols[e];
        cw.y = __float_as_int(w[e]);
        packed[slot] = cw;
    }
}

// ---------------- gather kernel: one wave per row ----------------

__global__ __launch_bounds__(256) void spmm_csr_kernel(
    const float* __restrict__ x, const int* __restrict__ start,
    const int2* __restrict__ packed, float* __restrict__ out, int N) {
    int wid = (int)((blockIdx.x * 256 + threadIdx.x) >> 6);  // row id
    int lane = threadIdx.x & 63;
    if (wid >= N) return;

    int s = start[wid];
    int t = start[wid + 1];
    const float2* x2 = reinterpret_cast<const float2*>(x);
    const long long* pk = reinterpret_cast<const long long*>(packed);
    float accx = 0.f, accy = 0.f;

    int e = s;
    for (; e + 3 < t; e += 4) {
        long long cw0 = __builtin_nontemporal_load(pk + e);
        long long cw1 = __builtin_nontemporal_load(pk + e + 1);
        long long cw2 = __builtin_nontemporal_load(pk + e + 2);
        long long cw3 = __builtin_nontemporal_load(pk + e + 3);
        float2 v0 = x2[(size_t)(int)(cw0 & 0xffffffff) * 64 + lane];
        float2 v1 = x2[(size_t)(int)(cw1 & 0xffffffff) * 64 + lane];
        float2 v2 = x2[(size_t)(int)(cw2 & 0xffffffff) * 64 + lane];
        float2 v3 = x2[(size_t)(int)(cw3 & 0xffffffff) * 64 + lane];
        float w0 = __int_as_float((int)(cw0 >> 32));
        float w1 = __int_as_float((int)(cw1 >> 32));
        float w2 = __int_as_float((int)(cw2 >> 32));
        float w3 = __int_as_float((int)(cw3 >> 32));
        accx += w0 * v0.x; accy += w0 * v0.y;
        accx += w1 * v1.x; accy += w1 * v1.y;
        accx += w2 * v2.x; accy += w2 * v2.y;
        accx += w3 * v3.x; accy += w3 * v3.y;
    }
    for (; e < t; ++e) {
        long long cw = __builtin_nontemporal_load(pk + e);
        float2 v = x2[(size_t)(int)(cw & 0xffffffff) * 64 + lane];
        float w0 = __int_as_float((int)(cw >> 32));
        accx += w0 * v.x; accy += w0 * v.y;
    }
    f32x2 a; a.x = accx; a.y = accy;
    __builtin_nontemporal_store(a, reinterpret_cast<f32x2*>(out) + (size_t)wid * 64 + lane);
}

// ---------------- non-coop fallback path (round-2, 13.6MB ws) ----------------

__global__ __launch_bounds__(256) void hist_kernel(
    const int* __restrict__ rows, int* __restrict__ counts, int E) {
    int i = blockIdx.x * 256 + threadIdx.x;
    if (i < E) atomicAdd(&counts[rows[i]], 1);
}

__global__ __launch_bounds__(256) void scan1_kernel(
    int* __restrict__ start, int* __restrict__ bsums, int n) {
    __shared__ int tmp[256];
    int tid = threadIdx.x;
    int i = blockIdx.x * 256 + tid;
    int v = (i < n) ? start[i] : 0;
    tmp[tid] = v;
    __syncthreads();
    for (int off = 1; off < 256; off <<= 1) {
        int t = (tid >= off) ? tmp[tid - off] : 0;
        __syncthreads();
        tmp[tid] += t;
        __syncthreads();
    }
    if (i < n) start[i] = tmp[tid] - v;
    if (tid == 255) bsums[blockIdx.x] = tmp[255];
}

__global__ __launch_bounds__(512) void scan2_kernel(int* __restrict__ bsums, int nb) {
    __shared__ int tmp[512];
    int tid = threadIdx.x;
    int v = (tid < nb) ? bsums[tid] : 0;
    tmp[tid] = v;
    __syncthreads();
    for (int off = 1; off < 512; off <<= 1) {
        int t = (tid >= off) ? tmp[tid - off] : 0;
        __syncthreads();
        tmp[tid] += t;
        __syncthreads();
    }
    if (tid < nb) bsums[tid] = tmp[tid] - v;
}

__global__ __launch_bounds__(256) void scan3_kernel(
    int* __restrict__ start, const int* __restrict__ bsums,
    int* __restrict__ cursor, int n, int E) {
    int i = blockIdx.x * 256 + threadIdx.x;
    if (i < n) {
        int s = start[i] + bsums[blockIdx.x];
        start[i] = s;
        cursor[i] = s;
    }
    if (i == 0) start[n] = E;
}

__global__ __launch_bounds__(256) void scatter_kernel(
    const int* __restrict__ rows, const int* __restrict__ cols,
    const float* __restrict__ w, int* __restrict__ cursor,
    int2* __restrict__ packed, int E) {
    int i = blockIdx.x * 256 + threadIdx.x;
    if (i >= E) return;
    int r = rows[i];
    int p = atomicAdd(&cursor[r], 1);
    int2 cw;
    cw.x = cols[i];
    cw.y = __float_as_int(w[i]);
    packed[p] = cw;
}

__global__ __launch_bounds__(256) void spmm_scatter_kernel(
    const float* __restrict__ x, const int* __restrict__ edge_index,
    const float* __restrict__ edge_values, float* __restrict__ out, int E) {
    long long t = (long long)blockIdx.x * blockDim.x + threadIdx.x;
    int e = (int)(t >> 5);
    int part = (int)(t & 31);
    if (e >= E) return;
    int row = edge_index[e];
    int col = edge_index[E + e];
    float w = edge_values[e];
    const float4* xrow = reinterpret_cast<const float4*>(x + (size_t)col * D_FEAT);
    float4 v = xrow[part];
    float* o = out + (size_t)row * D_FEAT + part * 4;
    unsafeAtomicAdd(o + 0, v.x * w);
    unsafeAtomicAdd(o + 1, v.y * w);
    unsafeAtomicAdd(o + 2, v.z * w);
    unsafeAtomicAdd(o + 3, v.w * w);
}

// ---------------- launch ----------------

extern "C" void kernel_launch(void* const* d_in, const int* in_sizes, int n_in,
                              void* d_out, int out_size, void* d_ws, size_t ws_size,
                              hipStream_t stream) {
    const float* x           = (const float*)d_in[0];
    const int*   edge_index  = (const int*)d_in[1];
    const float* edge_values = (const float*)d_in[2];
    float*       out         = (float*)d_out;

    int E = in_sizes[2];
    int N = out_size / D_FEAT;
    const int* rows = edge_index;
    const int* cols = edge_index + E;
    int ntiles = (N + 255) / 256;

    // coop-path workspace: start(N+1) | bsums(512) | rank(E) | packed(E int2)
    size_t off = 0;
    int* start = (int*)((char*)d_ws + off); off += (size_t)(N + 1) * sizeof(int);
    int* bsums = (int*)((char*)d_ws + off); off += 512 * sizeof(int);
    int* rank  = (int*)((char*)d_ws + off); off += (size_t)E * sizeof(int);
    off = (off + 15) & ~(size_t)15;
    int2* packed = (int2*)((char*)d_ws + off); off += (size_t)E * sizeof(int2);

    if (off <= ws_size && ntiles <= 512) {
        void* args[] = {(void*)&rows, (void*)&cols, (void*)&edge_values,
                        (void*)&start, (void*)&bsums, (void*)&rank,
                        (void*)&packed, (void*)&N, (void*)&E, (void*)&ntiles};
        hipLaunchCooperativeKernel((void*)build_csr_coop, dim3(COOP_BLOCKS),
                                   dim3(COOP_THREADS), args, 0, stream);
        int blocks = (int)(((long long)N * 64 + 255) / 256);
        spmm_csr_kernel<<<blocks, 256, 0, stream>>>(x, start, packed, out, N);
        return;
    }

    // round-2 fallback: start(N+1) | cursor(N) | bsums(nb) | packed(E int2)
    off = 0;
    start       = (int*)((char*)d_ws + off); off += (size_t)(N + 1) * sizeof(int);
    int* cursor = (int*)((char*)d_ws + off); off += (size_t)N * sizeof(int);
    int nb = (N + 255) / 256;
    bsums       = (int*)((char*)d_ws + off); off += (size_t)nb * sizeof(int);
    off = (off + 15) & ~(size_t)15;
    packed      = (int2*)((char*)d_ws + off); off += (size_t)E * sizeof(int2);

    if (off <= ws_size && nb <= 512) {
        hipMemsetAsync(start, 0, (size_t)(N + 1) * sizeof(int), stream);
        int ebl = (E + 255) / 256;
        hist_kernel<<<ebl, 256, 0, stream>>>(rows, start, E);
        scan1_kernel<<<nb, 256, 0, stream>>>(start, bsums, N);
        scan2_kernel<<<1, 512, 0, stream>>>(bsums, nb);
        scan3_kernel<<<nb, 256, 0, stream>>>(start, bsums, cursor, N, E);
        scatter_kernel<<<ebl, 256, 0, stream>>>(rows, cols, edge_values, cursor, packed, E);
        int blocks = (int)(((long long)N * 64 + 255) / 256);
        spmm_csr_kernel<<<blocks, 256, 0, stream>>>(x, start, packed, out, N);
        return;
    }

    // last-resort: atomic scatter
    hipMemsetAsync(d_out, 0, (size_t)out_size * sizeof(float), stream);
    long long total_threads = (long long)E * 32;
    long long grid = (total_threads + 255) / 256;
    spmm_scatter_kernel<<<(dim3)(unsigned)grid, 256, 0, stream>>>(
        x, edge_index, edge_values, out, E);
}

// Round 4
// 229.011 us; speedup vs baseline: 3.0398x; 3.0398x over previous
//
#include <hip/hip_runtime.h>
#include <hip/hip_bf16.h>

// COO SpMM: out[row[e], :] += ev[e] * x[col[e], :]
// N=100000, E=1600000, D=128 fp32.
//
// Round 4: back to multi-dispatch preprocessing (coop kernel starved at 1024
// blocks), but keep the rank-capture trick: hist's returning atomicAdd gives
// each edge its within-row rank, so the scatter pass needs NO atomics.
// Pipeline: memset -> hist(+rank) -> scan1 -> scan2 -> scan3 -> scatter -> gather.

#define D_FEAT 128

typedef float f32x2 __attribute__((ext_vector_type(2)));

// ---------------- phase kernels ----------------

// Histogram with rank capture: one thread per edge, full-width atomics.
__global__ __launch_bounds__(256) void hist_rank_kernel(
    const int* __restrict__ rows, int* __restrict__ counts,
    int* __restrict__ rank, int E) {
    int i = blockIdx.x * 256 + threadIdx.x;
    if (i < E) rank[i] = atomicAdd(&counts[rows[i]], 1);
}

// Block-local exclusive scan (in place over counts->start) + per-block totals.
__global__ __launch_bounds__(256) void scan1_kernel(
    int* __restrict__ start, int* __restrict__ bsums, int n) {
    __shared__ int tmp[256];
    int tid = threadIdx.x;
    int i = blockIdx.x * 256 + tid;
    int v = (i < n) ? start[i] : 0;
    tmp[tid] = v;
    __syncthreads();
    for (int off = 1; off < 256; off <<= 1) {
        int t = (tid >= off) ? tmp[tid - off] : 0;
        __syncthreads();
        tmp[tid] += t;
        __syncthreads();
    }
    if (i < n) start[i] = tmp[tid] - v;   // exclusive within block
    if (tid == 255) bsums[blockIdx.x] = tmp[255];
}

// Single-block exclusive scan of block sums (nb <= 512).
__global__ __launch_bounds__(512) void scan2_kernel(int* __restrict__ bsums, int nb) {
    __shared__ int tmp[512];
    int tid = threadIdx.x;
    int v = (tid < nb) ? bsums[tid] : 0;
    tmp[tid] = v;
    __syncthreads();
    for (int off = 1; off < 512; off <<= 1) {
        int t = (tid >= off) ? tmp[tid - off] : 0;
        __syncthreads();
        tmp[tid] += t;
        __syncthreads();
    }
    if (tid < nb) bsums[tid] = tmp[tid] - v;
}

// Add scanned block offsets; set start[n] = E.
__global__ __launch_bounds__(256) void scan3_kernel(
    int* __restrict__ start, const int* __restrict__ bsums, int n, int E) {
    int i = blockIdx.x * 256 + threadIdx.x;
    if (i < n) start[i] += bsums[blockIdx.x];
    if (i == 0) start[n] = E;
}

// Scatter edges into row-sorted packed (col, w) pairs. NO atomics.
__global__ __launch_bounds__(256) void scatter_norank_atomic_kernel(
    const int* __restrict__ rows, const int* __restrict__ cols,
    const float* __restrict__ w, const int* __restrict__ start,
    const int* __restrict__ rank, int2* __restrict__ packed, int E) {
    int i = blockIdx.x * 256 + threadIdx.x;
    if (i >= E) return;
    int slot = start[rows[i]] + rank[i];
    int2 cw;
    cw.x = cols[i];
    cw.y = __float_as_int(w[i]);
    packed[slot] = cw;
}

// One wave per row: gather x[col] (float2/lane), accumulate in regs, write once.
__global__ __launch_bounds__(256) void spmm_csr_kernel(
    const float* __restrict__ x, const int* __restrict__ start,
    const int2* __restrict__ packed, float* __restrict__ out, int N) {
    int wid = (int)((blockIdx.x * 256 + threadIdx.x) >> 6);  // row id
    int lane = threadIdx.x & 63;
    if (wid >= N) return;

    int s = start[wid];
    int t = start[wid + 1];
    const float2* x2 = reinterpret_cast<const float2*>(x);
    const long long* pk = reinterpret_cast<const long long*>(packed);
    float accx = 0.f, accy = 0.f;

    int e = s;
    for (; e + 3 < t; e += 4) {
        long long cw0 = __builtin_nontemporal_load(pk + e);
        long long cw1 = __builtin_nontemporal_load(pk + e + 1);
        long long cw2 = __builtin_nontemporal_load(pk + e + 2);
        long long cw3 = __builtin_nontemporal_load(pk + e + 3);
        float2 v0 = x2[(size_t)(int)(cw0 & 0xffffffff) * 64 + lane];
        float2 v1 = x2[(size_t)(int)(cw1 & 0xffffffff) * 64 + lane];
        float2 v2 = x2[(size_t)(int)(cw2 & 0xffffffff) * 64 + lane];
        float2 v3 = x2[(size_t)(int)(cw3 & 0xffffffff) * 64 + lane];
        float w0 = __int_as_float((int)(cw0 >> 32));
        float w1 = __int_as_float((int)(cw1 >> 32));
        float w2 = __int_as_float((int)(cw2 >> 32));
        float w3 = __int_as_float((int)(cw3 >> 32));
        accx += w0 * v0.x; accy += w0 * v0.y;
        accx += w1 * v1.x; accy += w1 * v1.y;
        accx += w2 * v2.x; accy += w2 * v2.y;
        accx += w3 * v3.x; accy += w3 * v3.y;
    }
    for (; e < t; ++e) {
        long long cw = __builtin_nontemporal_load(pk + e);
        float2 v = x2[(size_t)(int)(cw & 0xffffffff) * 64 + lane];
        float w0 = __int_as_float((int)(cw >> 32));
        accx += w0 * v.x; accy += w0 * v.y;
    }
    f32x2 a; a.x = accx; a.y = accy;
    __builtin_nontemporal_store(a, reinterpret_cast<f32x2*>(out) + (size_t)wid * 64 + lane);
}

// ---------------- last-resort fallback (round-1 atomic path) ----------------

__global__ __launch_bounds__(256) void spmm_scatter_kernel(
    const float* __restrict__ x, const int* __restrict__ edge_index,
    const float* __restrict__ edge_values, float* __restrict__ out, int E) {
    long long t = (long long)blockIdx.x * blockDim.x + threadIdx.x;
    int e = (int)(t >> 5);
    int part = (int)(t & 31);
    if (e >= E) return;
    int row = edge_index[e];
    int col = edge_index[E + e];
    float w = edge_values[e];
    const float4* xrow = reinterpret_cast<const float4*>(x + (size_t)col * D_FEAT);
    float4 v = xrow[part];
    float* o = out + (size_t)row * D_FEAT + part * 4;
    unsafeAtomicAdd(o + 0, v.x * w);
    unsafeAtomicAdd(o + 1, v.y * w);
    unsafeAtomicAdd(o + 2, v.z * w);
    unsafeAtomicAdd(o + 3, v.w * w);
}

// ---------------- launch ----------------

extern "C" void kernel_launch(void* const* d_in, const int* in_sizes, int n_in,
                              void* d_out, int out_size, void* d_ws, size_t ws_size,
                              hipStream_t stream) {
    const float* x           = (const float*)d_in[0];
    const int*   edge_index  = (const int*)d_in[1];
    const float* edge_values = (const float*)d_in[2];
    float*       out         = (float*)d_out;

    int E = in_sizes[2];
    int N = out_size / D_FEAT;
    const int* rows = edge_index;
    const int* cols = edge_index + E;
    int nb = (N + 255) / 256;   // scan tiles

    // workspace: start(N+1) | bsums(512) | rank(E) | packed(E int2)
    size_t off = 0;
    int* start = (int*)((char*)d_ws + off); off += (size_t)(N + 1) * sizeof(int);
    int* bsums = (int*)((char*)d_ws + off); off += 512 * sizeof(int);
    int* rank  = (int*)((char*)d_ws + off); off += (size_t)E * sizeof(int);
    off = (off + 15) & ~(size_t)15;
    int2* packed = (int2*)((char*)d_ws + off); off += (size_t)E * sizeof(int2);

    if (off <= ws_size && nb <= 512) {
        int ebl = (E + 255) / 256;
        // 1) zero histogram
        hipMemsetAsync(start, 0, (size_t)(N + 1) * sizeof(int), stream);
        // 2) histogram of rows, capturing per-edge rank (one atomic pass total)
        hist_rank_kernel<<<ebl, 256, 0, stream>>>(rows, start, rank, E);
        // 3) exclusive scan -> CSR start offsets
        scan1_kernel<<<nb, 256, 0, stream>>>(start, bsums, N);
        scan2_kernel<<<1, 512, 0, stream>>>(bsums, nb);
        scan3_kernel<<<nb, 256, 0, stream>>>(start, bsums, N, E);
        // 4) scatter edges to sorted slots (pure BW, no atomics)
        scatter_norank_atomic_kernel<<<ebl, 256, 0, stream>>>(
            rows, cols, edge_values, start, rank, packed, E);
        // 5) gather-accumulate, one wave per row, single write per output row
        int blocks = (int)(((long long)N * 64 + 255) / 256);
        spmm_csr_kernel<<<blocks, 256, 0, stream>>>(x, start, packed, out, N);
        return;
    }

    // last-resort: atomic scatter
    hipMemsetAsync(d_out, 0, (size_t)out_size * sizeof(float), stream);
    long long total_threads = (long long)E * 32;
    long long grid = (total_threads + 255) / 256;
    spmm_scatter_kernel<<<(dim3)(unsigned)grid, 256, 0, stream>>>(
        x, edge_index, edge_values, out, E);
}